// Round 3
// baseline (206.272 us; speedup 1.0000x reference)
//
#include <hip/hip_runtime.h>
#include <hip/hip_bf16.h>

// B=8, N=256, D=128, E=32, H=4, HD=32
// ws layout (float offsets)
#define OFF_WKE 0          // 4096: wk@edge_w  (D x E)
#define OFF_WVE 4096       // 4096: wv@edge_w
#define OFF_KB  8192       // 128: wk@edge_b + bk
#define OFF_VB  8320       // 128: wv@edge_b + bv
#define OFF_QS  8448       // 262144: q/sqrt(HD) per row
#define OFF_HG  270592     // 262144: gcn branch output (incl gcn_b)
#define OFF_K0  532736     // bf16 x 262144 (131072 float slots)
#define OFF_V0  663808     // bf16 x 262144
// total 794880 floats = 3.18 MB

static __device__ __forceinline__ float bflo(unsigned int w){
  union { unsigned int u; float f; } x; x.u = w << 16; return x.f;
}
static __device__ __forceinline__ float bfhi(unsigned int w){
  union { unsigned int u; float f; } x; x.u = w & 0xffff0000u; return x.f;
}
static __device__ __forceinline__ unsigned int f2bf(float f){
  union { float f; unsigned int u; } x; x.f = f;
  return (x.u + 0x7fffu + ((x.u >> 16) & 1u)) >> 16;
}

// ---------------------------------------------------------------------------
// Kernel 1: per-row q/K0/V0 (direct row-major weight reads), GCN branch,
// and (blocks 0..32) the tiny fused-weight prep. 4 rows/block, grid 512.
// ---------------------------------------------------------------------------
__global__ __launch_bounds__(256) void proj_kernel(
    const float* __restrict__ h, const float* __restrict__ adj,
    const float* __restrict__ gcn_w, const float* __restrict__ gcn_b,
    const float* __restrict__ edge_w, const float* __restrict__ edge_b,
    const float* __restrict__ wq, const float* __restrict__ wk,
    const float* __restrict__ wv, const float* __restrict__ bq,
    const float* __restrict__ bk, const float* __restrict__ bv,
    float* __restrict__ ws)
{
  __shared__ float h_lds[4*128];
  __shared__ float adj_lds[4*256];
  __shared__ float p1[2][4][128];
  __shared__ float p2[2][4][128];
  __shared__ float p3[2][4][128];
  __shared__ float ha_lds[4*132];
  __shared__ float dpart[2][4];

  int t = threadIdx.x;
  int d = t & 127, kh = t >> 7;
  int b = blockIdx.x >> 6;
  int n0 = (blockIdx.x & 63) * 4;
  int r0 = b*256 + n0;

  if (t < 128) ((float4*)h_lds)[t] = ((const float4*)(h + (size_t)r0*128))[t];
  ((float4*)adj_lds)[t] = ((const float4*)(adj + (size_t)r0*256))[t];
  __syncthreads();

  // --- q/k/v matvecs: direct row-major weight reads (per-thread contiguous) ---
  {
    const float4* wq4 = (const float4*)(wq + (size_t)d*128 + kh*64);
    const float4* wk4 = (const float4*)(wk + (size_t)d*128 + kh*64);
    const float4* wv4 = (const float4*)(wv + (size_t)d*128 + kh*64);
    float aq[4]={0,0,0,0}, ak[4]={0,0,0,0}, av[4]={0,0,0,0};
    #pragma unroll
    for (int kk = 0; kk < 16; ++kk) {
      float4 qw = wq4[kk], kw = wk4[kk], vw = wv4[kk];
      int k0 = kh*64 + kk*4;
      #pragma unroll
      for (int i = 0; i < 4; ++i) {
        const float* hr = h_lds + i*128 + k0;
        aq[i] += qw.x*hr[0] + qw.y*hr[1] + qw.z*hr[2] + qw.w*hr[3];
        ak[i] += kw.x*hr[0] + kw.y*hr[1] + kw.z*hr[2] + kw.w*hr[3];
        av[i] += vw.x*hr[0] + vw.y*hr[1] + vw.z*hr[2] + vw.w*hr[3];
      }
    }
    #pragma unroll
    for (int i = 0; i < 4; ++i) { p1[kh][i][d]=aq[i]; p2[kh][i][d]=ak[i]; p3[kh][i][d]=av[i]; }
  }
  __syncthreads();

  unsigned short* K0 = (unsigned short*)(ws + OFF_K0);
  unsigned short* V0 = (unsigned short*)(ws + OFF_V0);
  if (t < 128) {
    const float inv = 0.17677669529663687f;  // 1/sqrt(32)
    #pragma unroll
    for (int i = 0; i < 4; ++i) {
      ws[OFF_QS + (size_t)(r0+i)*128 + d] = (p1[0][i][d] + p1[1][i][d] + bq[d]) * inv;
      K0[(size_t)(r0+i)*128 + d] = (unsigned short)f2bf(p2[0][i][d] + p2[1][i][d]);
      V0[(size_t)(r0+i)*128 + d] = (unsigned short)f2bf(p3[0][i][d] + p3[1][i][d]);
    }
  }
  __syncthreads();

  // --- GCN aggregation (reuses p1) ---
  {
    float ag[4]={0,0,0,0}, dg[4]={0,0,0,0};
    for (int mm = 0; mm < 128; ++mm) {
      int ml = kh*128 + mm;
      float hv = h[((size_t)b*256 + ml)*128 + d];
      #pragma unroll
      for (int i = 0; i < 4; ++i) {
        float a = adj_lds[i*256 + ml] + ((ml == n0 + i) ? 1.0f : 0.0f);
        ag[i] += a * hv;
        dg[i] += a;
      }
    }
    #pragma unroll
    for (int i = 0; i < 4; ++i) p1[kh][i][d] = ag[i];
    if (d == 0) {
      #pragma unroll
      for (int i = 0; i < 4; ++i) dpart[kh][i] = dg[i];
    }
  }
  __syncthreads();
  if (t < 128) {
    #pragma unroll
    for (int i = 0; i < 4; ++i)
      ha_lds[i*132 + d] = (p1[0][i][d] + p1[1][i][d]) / (dpart[0][i] + dpart[1][i]);
  }
  __syncthreads();

  // --- gcn matvec (direct row-major) -> HG = h_agg@gcn_w^T + gcn_b ---
  {
    const float4* gw4 = (const float4*)(gcn_w + (size_t)d*128 + kh*64);
    float ga[4]={0,0,0,0};
    #pragma unroll
    for (int kk = 0; kk < 16; ++kk) {
      float4 g4 = gw4[kk];
      int k0 = kh*64 + kk*4;
      #pragma unroll
      for (int i = 0; i < 4; ++i) {
        const float* hr = ha_lds + i*132 + k0;
        ga[i] += g4.x*hr[0] + g4.y*hr[1] + g4.z*hr[2] + g4.w*hr[3];
      }
    }
    #pragma unroll
    for (int i = 0; i < 4; ++i) p2[kh][i][d] = ga[i];
  }
  __syncthreads();
  if (t < 128) {
    #pragma unroll
    for (int i = 0; i < 4; ++i)
      ws[OFF_HG + (size_t)(r0+i)*128 + d] = p2[0][i][d] + p2[1][i][d] + gcn_b[d];
  }

  // --- tiny prep duty on low blocks ---
  if (blockIdx.x < 32) {
    int which = blockIdx.x >> 4;            // 0: Wke, 1: Wve
    int e0 = (blockIdx.x & 15) * 256 + t;   // [0,4096)
    int dd = e0 >> 5, e = e0 & 31;
    const float* W = which ? wv : wk;
    float acc = 0.f;
    #pragma unroll 4
    for (int k2 = 0; k2 < 128; ++k2) acc += W[dd*128+k2] * edge_w[k2*32+e];
    ws[(which ? OFF_WVE : OFF_WKE) + e0] = acc;
  } else if (blockIdx.x == 32) {
    int dd = t & 127;
    const float* W  = (t < 128) ? wk : wv;
    const float* bb = (t < 128) ? bk : bv;
    float acc = bb[dd];
    #pragma unroll 4
    for (int k2 = 0; k2 < 128; ++k2) acc += W[dd*128+k2] * edge_b[k2];
    ws[((t < 128) ? OFF_KB : OFF_VB) + dd] = acc;
  }
}

// ---------------------------------------------------------------------------
// Kernel 2: fused attention + out-proj + residual + LN + gcn-add per (b,n).
// Coalesced edge load. LDS ~31.3 KB -> 5 blocks/CU. Writes d_out directly.
// ---------------------------------------------------------------------------
__global__ __launch_bounds__(256, 5) void attn_kernel(
    const float* __restrict__ edge, const float* __restrict__ adj,
    const float* __restrict__ srcm, const float* __restrict__ h,
    const float* __restrict__ out_w, const float* __restrict__ out_b,
    const float* __restrict__ ln_g, const float* __restrict__ ln_b,
    const float* __restrict__ ws, float* __restrict__ out)
{
  __shared__ unsigned int e_bf[256*18];   // bf16-packed edge rows (stride 18 u32)
  __shared__ float s_lds[1028];           // 4 heads x stride 257
  __shared__ float part4[8*132];          // ebar partials; later o_l / xl
  __shared__ float part5[8*132];          // o partials; later out-proj partials
  __shared__ float ebar[128];
  __shared__ float qs_l[128];
  __shared__ float qe_l[128];
  __shared__ float sc_l[4];
  __shared__ float red[8];

  int t  = threadIdx.x;
  int bn = blockIdx.x;
  int b  = bn >> 8;

  // ---- Phase 0: coalesced edge tile -> bf16 LDS; mask + qs ----
  {
    const float4* et = (const float4*)(edge + (size_t)bn*8192);
    #pragma unroll
    for (int it = 0; it < 8; ++it) {
      int fi = it*256 + t;
      float4 v = et[fi];
      int row = fi >> 3, c4 = fi & 7;
      uint2 pk;
      pk.x = f2bf(v.x) | (f2bf(v.y) << 16);
      pk.y = f2bf(v.z) | (f2bf(v.w) << 16);
      *(uint2*)(e_bf + row*18 + c4*2) = pk;
    }
  }
  float ma  = adj[(size_t)bn*256 + t];
  float msk = srcm[(size_t)bn*256 + t];
  if (t < 128) qs_l[t] = ws[OFF_QS + (size_t)bn*128 + t];
  __syncthreads();

  // ---- Phase 0b: qe = Wke^T-ish contraction; sconst = q.kbias ----
  if (t < 128) {
    int hh = t >> 5, e = t & 31;
    float acc = 0.f;
    #pragma unroll
    for (int j = 0; j < 32; ++j)
      acc += ws[OFF_WKE + (hh*32 + j)*32 + e] * qs_l[hh*32 + j];
    qe_l[t] = acc;
  } else if (t < 132) {
    int hh = t - 128;
    float acc = 0.f;
    #pragma unroll
    for (int j = 0; j < 32; ++j)
      acc += qs_l[hh*32 + j] * ws[OFF_KB + hh*32 + j];
    sc_l[hh] = acc;
  }
  __syncthreads();

  // ---- Phase 1: scores for m = t ----
  int m = t;
  float s4[4];
  {
    float e32[32];
    const uint2* er = (const uint2*)(e_bf + m*18);
    #pragma unroll
    for (int j = 0; j < 8; ++j) {
      uint2 w = er[j];
      e32[4*j+0] = bflo(w.x); e32[4*j+1] = bfhi(w.x);
      e32[4*j+2] = bflo(w.y); e32[4*j+3] = bfhi(w.y);
    }
    const uint4* kv = (const uint4*)((const unsigned short*)(ws + OFF_K0)
                                     + (size_t)(b*256 + m)*128);
    #pragma unroll
    for (int hh = 0; hh < 4; ++hh) {
      float acc = sc_l[hh];
      #pragma unroll
      for (int q4 = 0; q4 < 4; ++q4) {
        uint4 kw = kv[hh*4 + q4];
        const float* qp = qs_l + hh*32 + q4*8;
        acc += qp[0]*bflo(kw.x) + qp[1]*bfhi(kw.x)
             + qp[2]*bflo(kw.y) + qp[3]*bfhi(kw.y)
             + qp[4]*bflo(kw.z) + qp[5]*bfhi(kw.z)
             + qp[6]*bflo(kw.w) + qp[7]*bfhi(kw.w);
      }
      const float* qep = qe_l + hh*32;
      #pragma unroll
      for (int j = 0; j < 32; ++j) acc += qep[j]*e32[j];
      s4[hh] = acc;
    }
    if (ma * msk == 0.0f) { s4[0] = s4[1] = s4[2] = s4[3] = -1e30f; }
    #pragma unroll
    for (int hh = 0; hh < 4; ++hh) s_lds[hh*257 + m] = s4[hh];
  }
  __syncthreads();

  // ---- Phase 2: per-head softmax stats ----
  {
    int wvh = t >> 6, ln = t & 63;
    float v0 = s_lds[wvh*257 + ln];
    float v1 = s_lds[wvh*257 + ln + 64];
    float v2 = s_lds[wvh*257 + ln + 128];
    float v3 = s_lds[wvh*257 + ln + 192];
    float mx = fmaxf(fmaxf(v0, v1), fmaxf(v2, v3));
    #pragma unroll
    for (int off = 32; off > 0; off >>= 1) mx = fmaxf(mx, __shfl_down(mx, off));
    mx = __shfl(mx, 0);
    float sm = __expf(v0-mx) + __expf(v1-mx) + __expf(v2-mx) + __expf(v3-mx);
    #pragma unroll
    for (int off = 32; off > 0; off >>= 1) sm += __shfl_down(sm, off);
    if (ln == 0) { red[wvh] = mx; red[4+wvh] = 1.0f / sm; }
  }
  __syncthreads();

  // ---- Phase 3: attn weights ----
  #pragma unroll
  for (int hh = 0; hh < 4; ++hh)
    s_lds[hh*257 + m] = __expf(s4[hh] - red[hh]) * red[4+hh];
  __syncthreads();

  // ---- Phase 4+5: ebar partials + o partials in one m-sweep ----
  {
    int ms  = t >> 5;
    int hh4 = (t >> 3) & 3, e4 = t & 7;
    int c   = t & 31,  hh5 = c >> 3;
    float p4x=0,p4y=0,p4z=0,p4w=0;
    float p5x=0,p5y=0,p5z=0,p5w=0;
    const unsigned int* vrow = (const unsigned int*)(ws + OFF_V0) + (size_t)b*256*64;
    for (int jm = 0; jm < 32; ++jm) {
      int mm = ms*32 + jm;
      float a4 = s_lds[hh4*257 + mm];
      uint2 w = *(const uint2*)(e_bf + mm*18 + e4*2);
      p4x += a4*bflo(w.x); p4y += a4*bfhi(w.x);
      p4z += a4*bflo(w.y); p4w += a4*bfhi(w.y);
      float a5 = s_lds[hh5*257 + mm];
      uint2 vv = *(const uint2*)(vrow + (size_t)mm*64 + c*2);
      p5x += a5*bflo(vv.x); p5y += a5*bfhi(vv.x);
      p5z += a5*bflo(vv.y); p5w += a5*bfhi(vv.y);
    }
    float4 f4; f4.x=p4x; f4.y=p4y; f4.z=p4z; f4.w=p4w;
    *(float4*)(part4 + ms*132 + hh4*32 + e4*4) = f4;
    float4 f5; f5.x=p5x; f5.y=p5y; f5.z=p5z; f5.w=p5w;
    *(float4*)(part5 + ms*132 + c*4) = f5;
  }
  __syncthreads();

  // ---- Phase 6a: reduce partials ----
  float s2 = 0.f;
  if (t < 128) {
    float se = 0.f;
    #pragma unroll
    for (int g = 0; g < 8; ++g) { se += part4[g*132 + t]; s2 += part5[g*132 + t]; }
    ebar[t] = se;
  }
  __syncthreads();

  // ---- Phase 6b: o = o_pre + Wve@ebar + vbias -> part4[0..127] ----
  if (t < 128) {
    int hh = t >> 5;
    float acc = s2 + ws[OFF_VB + t];
    const float* wve = ws + OFF_WVE + (size_t)t*32;
    #pragma unroll
    for (int e = 0; e < 32; ++e) acc += wve[e] * ebar[hh*32 + e];
    part4[t] = acc;
  }
  float hv = (t < 128) ? h[(size_t)bn*128 + t] : 0.f;
  __syncthreads();

  // ---- Phase 7: out-proj partials (direct row-major out_w) ----
  {
    int d = t & 127, kh = t >> 7;
    const float4* ow4 = (const float4*)(out_w + (size_t)d*128 + kh*64);
    float xa = 0.f;
    #pragma unroll
    for (int kk = 0; kk < 16; ++kk) {
      float4 w4 = ow4[kk];
      const float* op = part4 + kh*64 + kk*4;
      xa += w4.x*op[0] + w4.y*op[1] + w4.z*op[2] + w4.w*op[3];
    }
    part5[kh*128 + d] = xa;
  }
  __syncthreads();

  // ---- Phase 8: x = h + o@ow^T + out_b ----
  float x = 0.f;
  if (t < 128) {
    x = part5[t] + part5[128 + t] + out_b[t] + hv;
    part4[256 + t] = x;
  }
  __syncthreads();

  // ---- Phase 9: LN stats (one wave) ----
  if (t < 64) {
    float x0 = part4[256 + t], x1 = part4[256 + t + 64];
    float s = x0 + x1, ss = x0*x0 + x1*x1;
    #pragma unroll
    for (int off = 32; off > 0; off >>= 1) {
      s  += __shfl_down(s,  off);
      ss += __shfl_down(ss, off);
    }
    if (t == 0) {
      float mu = s * (1.0f/128.0f);
      red[0] = mu;
      red[1] = rsqrtf(ss * (1.0f/128.0f) - mu*mu + 1e-5f);
    }
  }
  __syncthreads();

  // ---- Phase 10: final write: LN + gcn branch ----
  if (t < 128) {
    float mu = red[0], rs = red[1];
    out[(size_t)bn*128 + t] =
        ln_g[t]*(x - mu)*rs + ln_b[t] + ws[OFF_HG + (size_t)bn*128 + t];
  }
}

// ---------------------------------------------------------------------------
extern "C" void kernel_launch(void* const* d_in, const int* in_sizes, int n_in,
                              void* d_out, int out_size, void* d_ws, size_t ws_size,
                              hipStream_t stream) {
  (void)in_sizes; (void)n_in; (void)out_size; (void)ws_size;
  const float* h     = (const float*)d_in[0];
  const float* adj   = (const float*)d_in[1];
  const float* edge  = (const float*)d_in[2];
  const float* srcm  = (const float*)d_in[3];
  const float* gcn_w = (const float*)d_in[4];
  const float* gcn_b = (const float*)d_in[5];
  const float* edge_w= (const float*)d_in[6];
  const float* edge_b= (const float*)d_in[7];
  const float* wq    = (const float*)d_in[8];
  const float* wk    = (const float*)d_in[9];
  const float* wv    = (const float*)d_in[10];
  const float* bq    = (const float*)d_in[11];
  const float* bk    = (const float*)d_in[12];
  const float* bv    = (const float*)d_in[13];
  const float* out_w = (const float*)d_in[14];
  const float* out_b = (const float*)d_in[15];
  const float* ln_g  = (const float*)d_in[16];
  const float* ln_b  = (const float*)d_in[17];

  float* ws  = (float*)d_ws;   // needs >= 3.18 MB
  float* out = (float*)d_out;

  proj_kernel<<<512, 256, 0, stream>>>(h, adj, gcn_w, gcn_b, edge_w, edge_b,
                                       wq, wk, wv, bq, bk, bv, ws);
  attn_kernel<<<2048, 256, 0, stream>>>(edge, adj, srcm, h, out_w, out_b,
                                        ln_g, ln_b, ws, out);
}

// Round 4
// 188.986 us; speedup vs baseline: 1.0915x; 1.0915x over previous
//
#include <hip/hip_runtime.h>
#include <hip/hip_bf16.h>

// B=8, N=256, D=128, E=32, H=4, HD=32
// ws layout (float offsets)
#define OFF_WQT 0          // 16384 transposed wq  [k][d]
#define OFF_WKT 16384
#define OFF_WVT 32768
#define OFF_OWT 49152      // transposed out_w [k][d]
#define OFF_GWT 65536      // transposed gcn_w [k][d]
#define OFF_WKE 81920      // 4096: wk@edge_w, row-major [d][e]
#define OFF_WVET 86016     // 4096: (wv@edge_w)^T, [e][d]
#define OFF_KB  90112      // 128
#define OFF_VB  90240      // 128
#define OFF_SC  90368      // 8192: per-row per-head score const
#define OFF_QS  98560      // 262144: q/sqrt(HD)
#define OFF_QE  360704     // 262144: Wke^T q per row
#define OFF_HG  622848     // 262144: gcn branch output (incl gcn_b)
#define OFF_K0  884992     // bf16 x 262144
#define OFF_V0  1016064    // bf16 x 262144
// total 1147136 floats = 4.59 MB

static __device__ __forceinline__ float bflo(unsigned int w){
  union { unsigned int u; float f; } x; x.u = w << 16; return x.f;
}
static __device__ __forceinline__ float bfhi(unsigned int w){
  union { unsigned int u; float f; } x; x.u = w & 0xffff0000u; return x.f;
}
static __device__ __forceinline__ unsigned int f2bf(float f){
  union { float f; unsigned int u; } x; x.f = f;
  return (x.u + 0x7fffu + ((x.u >> 16) & 1u)) >> 16;
}

// ---------------------------------------------------------------------------
// Kernel A (prep): 5 weight transposes + Wke / WveT + fused biases. ~4 us.
// ---------------------------------------------------------------------------
__global__ __launch_bounds__(256) void prep_kernel(
    const float* __restrict__ wq, const float* __restrict__ wk,
    const float* __restrict__ wv, const float* __restrict__ out_w,
    const float* __restrict__ gcn_w, const float* __restrict__ edge_w,
    const float* __restrict__ edge_b, const float* __restrict__ bk,
    const float* __restrict__ bv, float* __restrict__ ws)
{
  int blk = blockIdx.x, t = threadIdx.x;
  if (blk < 320) {
    int w = blk >> 6;
    int e0 = (blk & 63) * 256 + t;
    const float* src = (w==0) ? wq : (w==1) ? wk : (w==2) ? wv : (w==3) ? out_w : gcn_w;
    float* dst = ws + ((w==0) ? OFF_WQT : (w==1) ? OFF_WKT : (w==2) ? OFF_WVT
                      : (w==3) ? OFF_OWT : OFF_GWT);
    int k = e0 >> 7, d = e0 & 127;
    dst[e0] = src[d*128 + k];
  } else if (blk < 352) {
    int idx = blk - 320;
    int which = idx >> 4;                  // 0: Wke (row-major), 1: WveT (transposed)
    int e0 = (idx & 15) * 256 + t;
    int dd = e0 >> 5, e = e0 & 31;
    const float* W = which ? wv : wk;
    float acc = 0.f;
    #pragma unroll 4
    for (int k2 = 0; k2 < 128; ++k2) acc += W[dd*128+k2] * edge_w[k2*32+e];
    if (which) ws[OFF_WVET + e*128 + dd] = acc;
    else       ws[OFF_WKE + e0] = acc;
  } else {
    int dd = t & 127;
    const float* W  = (t < 128) ? wk : wv;
    const float* bb = (t < 128) ? bk : bv;
    float acc = bb[dd];
    #pragma unroll 4
    for (int k2 = 0; k2 < 128; ++k2) acc += W[dd*128+k2] * edge_b[k2];
    ws[((t < 128) ? OFF_KB : OFF_VB) + dd] = acc;
  }
}

// ---------------------------------------------------------------------------
// Kernel B (proj): qs/qe/sc, K0/V0 (bf16), GCN branch (HG).
// 2 rows/block, grid 1024 (4 blocks/CU). Transposed weights -> coalesced.
// ---------------------------------------------------------------------------
__global__ __launch_bounds__(256) void proj_kernel(
    const float* __restrict__ h, const float* __restrict__ adj,
    const float* __restrict__ bq, const float* __restrict__ gcn_b,
    float* __restrict__ ws)
{
  __shared__ float h_lds[256];        // 2 x 128
  __shared__ float adj_lds[512];      // 2 x 256
  __shared__ float p1[2][2][128];
  __shared__ float p2[2][2][128];
  __shared__ float p3[2][2][128];
  __shared__ float qrow[2*132];
  __shared__ float dpart[2][2];
  __shared__ float ha_lds[2*132];

  int t = threadIdx.x;
  int d = t & 127, kh = t >> 7;
  int r0 = blockIdx.x * 2;
  int b  = r0 >> 8, n0 = r0 & 255;

  if (t < 64)  ((float4*)h_lds)[t]   = ((const float4*)(h   + (size_t)r0*128))[t];
  if (t < 128) ((float4*)adj_lds)[t] = ((const float4*)(adj + (size_t)r0*256))[t];
  __syncthreads();

  // --- qkv matvecs, transposed weights (lane-d coalesced, 2 lines/instr) ---
  {
    const float* wqT = ws + OFF_WQT;
    const float* wkT = ws + OFF_WKT;
    const float* wvT = ws + OFF_WVT;
    float aq0=0,aq1=0,ak0=0,ak1=0,av0=0,av1=0;
    #pragma unroll 4
    for (int kk = 0; kk < 64; ++kk) {
      int k = kh*64 + kk;
      float qw = wqT[k*128+d], kw = wkT[k*128+d], vw = wvT[k*128+d];
      float h0 = h_lds[k], h1 = h_lds[128+k];
      aq0 += qw*h0; aq1 += qw*h1;
      ak0 += kw*h0; ak1 += kw*h1;
      av0 += vw*h0; av1 += vw*h1;
    }
    p1[kh][0][d]=aq0; p1[kh][1][d]=aq1;
    p2[kh][0][d]=ak0; p2[kh][1][d]=ak1;
    p3[kh][0][d]=av0; p3[kh][1][d]=av1;
  }
  __syncthreads();

  {
    unsigned short* K0 = (unsigned short*)(ws + OFF_K0);
    unsigned short* V0 = (unsigned short*)(ws + OFF_V0);
    int i = t >> 7, dd = t & 127;
    const float inv = 0.17677669529663687f;   // 1/sqrt(32)
    float q = (p1[0][i][dd] + p1[1][i][dd] + bq[dd]) * inv;
    ws[OFF_QS + (size_t)(r0+i)*128 + dd] = q;
    qrow[i*132 + dd] = q;
    K0[(size_t)(r0+i)*128 + dd] = (unsigned short)f2bf(p2[0][i][dd] + p2[1][i][dd]);
    V0[(size_t)(r0+i)*128 + dd] = (unsigned short)f2bf(p3[0][i][dd] + p3[1][i][dd]);
  }
  __syncthreads();   // qrow ready; p1..p3 free

  // --- GCN aggregation ---
  {
    float ag0=0, ag1=0, dg0=0, dg1=0;
    #pragma unroll 4
    for (int mm = 0; mm < 128; ++mm) {
      int ml = kh*128 + mm;
      float hv = h[((size_t)b*256 + ml)*128 + d];
      float a0 = adj_lds[ml]       + ((ml == n0)     ? 1.0f : 0.0f);
      float a1 = adj_lds[256 + ml] + ((ml == n0 + 1) ? 1.0f : 0.0f);
      ag0 += a0*hv; ag1 += a1*hv; dg0 += a0; dg1 += a1;
    }
    p1[kh][0][d]=ag0; p1[kh][1][d]=ag1;
    if (d == 0) { dpart[kh][0]=dg0; dpart[kh][1]=dg1; }
  }
  // --- qe + sc (uses qrow, independent of agg partials) ---
  {
    int i = t >> 7, he = t & 127, hh = he >> 5, e = he & 31;
    float acc = 0.f;
    #pragma unroll
    for (int j = 0; j < 32; ++j)
      acc += ws[OFF_WKE + (hh*32 + j)*32 + e] * qrow[i*132 + hh*32 + j];
    ws[OFF_QE + (size_t)(r0+i)*128 + he] = acc;
  }
  if (t < 8) {
    int i = t >> 2, hh = t & 3;
    float acc = 0.f;
    #pragma unroll
    for (int j = 0; j < 32; ++j)
      acc += qrow[i*132 + hh*32 + j] * ws[OFF_KB + hh*32 + j];
    ws[OFF_SC + (size_t)(r0+i)*4 + hh] = acc;
  }
  __syncthreads();

  {
    int i = t >> 7, dd = t & 127;
    ha_lds[i*132 + dd] = (p1[0][i][dd] + p1[1][i][dd]) / (dpart[0][i] + dpart[1][i]);
  }
  __syncthreads();

  // --- gcn matvec (transposed, coalesced) ---
  {
    const float* gwT = ws + OFF_GWT;
    float g0=0, g1=0;
    #pragma unroll 4
    for (int kk = 0; kk < 64; ++kk) {
      int k = kh*64 + kk;
      float gw = gwT[k*128+d];
      g0 += gw * ha_lds[k];
      g1 += gw * ha_lds[132 + k];
    }
    p2[kh][0][d]=g0; p2[kh][1][d]=g1;
  }
  __syncthreads();
  {
    int i = t >> 7, dd = t & 127;
    ws[OFF_HG + (size_t)(r0+i)*128 + dd] = p2[0][i][dd] + p2[1][i][dd] + gcn_b[dd];
  }
}

// ---------------------------------------------------------------------------
// Kernel C (attn): scores + softmax + weighted sums + out-proj + LN + add.
// One block per (b,n). 7 barriers. LDS ~32 KB -> 4 blocks/CU.
// ---------------------------------------------------------------------------
__global__ __launch_bounds__(256, 4) void attn_kernel(
    const float* __restrict__ edge, const float* __restrict__ adj,
    const float* __restrict__ srcm, const float* __restrict__ h,
    const float* __restrict__ out_b, const float* __restrict__ ln_g,
    const float* __restrict__ ln_b, const float* __restrict__ ws,
    float* __restrict__ out)
{
  __shared__ unsigned int e_bf[256*18];   // bf16 edge rows (16 used + 2 hole)
  __shared__ float s_lds[4*264];          // ex values, stride 264
  __shared__ float part4[8*132];          // ebar partials; later o / x
  __shared__ float part5[8*132];          // o partials
  __shared__ float qs_l[132];             // stride 33 per head
  __shared__ float qe_l[132];
  __shared__ float sc_l[4];
  __shared__ float ebar[128];
  __shared__ float wpart[16];
  __shared__ float red[2];

  int t  = threadIdx.x;
  int bn = blockIdx.x;
  int b  = bn >> 8;

  // ---- P1: coalesced edge tile -> bf16 LDS; qs/qe/sc -> LDS; mask -> holes ----
  {
    const float4* et = (const float4*)(edge + (size_t)bn*8192);
    #pragma unroll
    for (int it = 0; it < 8; ++it) {
      int fi = it*256 + t;
      float4 v = et[fi];
      int row = fi >> 3, c4 = fi & 7;
      uint2 pk;
      pk.x = f2bf(v.x) | (f2bf(v.y) << 16);
      pk.y = f2bf(v.z) | (f2bf(v.w) << 16);
      *(uint2*)(e_bf + row*18 + c4*2) = pk;
    }
    float mp = adj[(size_t)bn*256 + t] * srcm[(size_t)bn*256 + t];
    e_bf[t*18 + 16] = __float_as_uint(mp);
    if (t < 128) {
      int hh = t >> 5, j = t & 31;
      qs_l[hh*33 + j] = ws[OFF_QS + (size_t)bn*128 + t];
      qe_l[hh*33 + j] = ws[OFF_QE + (size_t)bn*128 + t];
    }
    if (t < 4) sc_l[t] = ws[OFF_SC + (size_t)bn*4 + t];
  }
  __syncthreads();

  // ---- P2: scores. lane quad (m, head): K0 coalesced, e broadcast from LDS ----
  int hh = t & 3;
  {
    const float* qp  = qs_l + hh*33;
    const float* qep = qe_l + hh*33;
    float exsum = 0.f;
    const unsigned short* K0 = (const unsigned short*)(ws + OFF_K0) + (size_t)b*256*128;
    #pragma unroll 2
    for (int pass = 0; pass < 4; ++pass) {
      int mm = (pass << 6) | (t >> 2);
      const uint4* kv = (const uint4*)(K0 + (size_t)mm*128) + hh*4;
      float acc = sc_l[hh];
      #pragma unroll
      for (int q4 = 0; q4 < 4; ++q4) {
        uint4 kw = kv[q4];
        const float* qq = qp + q4*8;
        acc += qq[0]*bflo(kw.x) + qq[1]*bfhi(kw.x)
             + qq[2]*bflo(kw.y) + qq[3]*bfhi(kw.y)
             + qq[4]*bflo(kw.z) + qq[5]*bfhi(kw.z)
             + qq[6]*bflo(kw.w) + qq[7]*bfhi(kw.w);
      }
      const uint2* er = (const uint2*)(e_bf + mm*18);
      #pragma unroll
      for (int j = 0; j < 8; ++j) {
        uint2 w = er[j];
        acc += qep[4*j+0]*bflo(w.x) + qep[4*j+1]*bfhi(w.x)
             + qep[4*j+2]*bflo(w.y) + qep[4*j+3]*bfhi(w.y);
      }
      float mp = __uint_as_float(e_bf[mm*18 + 16]);
      float ex = (mp == 0.0f) ? 0.0f : __expf(acc);   // no max-sub: |s| << 88
      s_lds[hh*264 + mm] = ex;
      exsum += ex;
    }
    // quad-strided wave reduce: lanes 0..3 of each wave hold per-head sums
    exsum += __shfl_down(exsum, 4);
    exsum += __shfl_down(exsum, 8);
    exsum += __shfl_down(exsum, 16);
    exsum += __shfl_down(exsum, 32);
    if ((t & 63) < 4) wpart[(t >> 6)*4 + hh] = exsum;
  }
  __syncthreads();

  // ---- P3: denominators (all threads, no barrier) + weighted partial sums ----
  {
    float s0 = wpart[0]+wpart[4]+wpart[8]+wpart[12];
    float s1 = wpart[1]+wpart[5]+wpart[9]+wpart[13];
    float s2h = wpart[2]+wpart[6]+wpart[10]+wpart[14];
    float s3h = wpart[3]+wpart[7]+wpart[11]+wpart[15];

    int ms  = t >> 5;
    int hh4 = (t >> 3) & 3, e4 = t & 7;
    int c   = t & 31,  hh5 = c >> 3;
    float sum4 = (hh4==0)?s0:(hh4==1)?s1:(hh4==2)?s2h:s3h;
    float sum5 = (hh5==0)?s0:(hh5==1)?s1:(hh5==2)?s2h:s3h;
    float inv4 = 1.0f / sum4, inv5 = 1.0f / sum5;

    float p4x=0,p4y=0,p4z=0,p4w=0;
    float p5x=0,p5y=0,p5z=0,p5w=0;
    const unsigned int* vrow = (const unsigned int*)(ws + OFF_V0) + (size_t)b*256*64;
    for (int jm = 0; jm < 32; ++jm) {
      int mm = ms*32 + jm;
      float a4 = s_lds[hh4*264 + mm];
      uint2 w = *(const uint2*)(e_bf + mm*18 + e4*2);
      p4x += a4*bflo(w.x); p4y += a4*bfhi(w.x);
      p4z += a4*bflo(w.y); p4w += a4*bfhi(w.y);
      float a5 = s_lds[hh5*264 + mm];
      uint2 vv = *(const uint2*)(vrow + (size_t)mm*64 + c*2);
      p5x += a5*bflo(vv.x); p5y += a5*bfhi(vv.x);
      p5z += a5*bflo(vv.y); p5w += a5*bfhi(vv.y);
    }
    float4 f4; f4.x=p4x*inv4; f4.y=p4y*inv4; f4.z=p4z*inv4; f4.w=p4w*inv4;
    *(float4*)(part4 + ms*132 + hh4*32 + e4*4) = f4;
    float4 f5; f5.x=p5x*inv5; f5.y=p5y*inv5; f5.z=p5z*inv5; f5.w=p5w*inv5;
    *(float4*)(part5 + ms*132 + c*4) = f5;
  }
  __syncthreads();

  // ---- P6a: reduce partials -> ebar (LDS), s2 (reg) ----
  float s2 = 0.f;
  if (t < 128) {
    float se = 0.f;
    #pragma unroll
    for (int g = 0; g < 8; ++g) { se += part4[g*132 + t]; s2 += part5[g*132 + t]; }
    ebar[t] = se;
  }
  __syncthreads();

  // ---- P6b: o = o_pre + WveT@ebar + vbias -> part4[0..127] ----
  float hv = 0.f;
  if (t < 128) {
    int hd = t >> 5;
    float acc = s2 + ws[OFF_VB + t];
    const float* wveT = ws + OFF_WVET;
    #pragma unroll 4
    for (int e = 0; e < 32; ++e) acc += wveT[e*128 + t] * ebar[hd*32 + e];
    part4[t] = acc;
    hv = h[(size_t)bn*128 + t];
  }
  __syncthreads();

  // ---- P7: x = h + o@out_w^T + out_b (owT coalesced) -> part4[132..259] ----
  float x = 0.f;
  if (t < 128) {
    const float* owT = ws + OFF_OWT;
    float acc = out_b[t] + hv;
    #pragma unroll 8
    for (int k = 0; k < 128; ++k) acc += owT[k*128 + t] * part4[k];
    x = acc;
    part4[132 + t] = x;
  }
  __syncthreads();

  // ---- P8: LN stats ----
  if (t < 64) {
    float x0 = part4[132 + t], x1 = part4[132 + t + 64];
    float s = x0 + x1, ss = x0*x0 + x1*x1;
    #pragma unroll
    for (int off = 32; off > 0; off >>= 1) {
      s  += __shfl_down(s,  off);
      ss += __shfl_down(ss, off);
    }
    if (t == 0) {
      float mu = s * (1.0f/128.0f);
      red[0] = mu;
      red[1] = rsqrtf(ss * (1.0f/128.0f) - mu*mu + 1e-5f);
    }
  }
  __syncthreads();

  // ---- P9: write ----
  if (t < 128) {
    float mu = red[0], rs = red[1];
    out[(size_t)bn*128 + t] =
        ln_g[t]*(x - mu)*rs + ln_b[t] + ws[OFF_HG + (size_t)bn*128 + t];
  }
}

// ---------------------------------------------------------------------------
extern "C" void kernel_launch(void* const* d_in, const int* in_sizes, int n_in,
                              void* d_out, int out_size, void* d_ws, size_t ws_size,
                              hipStream_t stream) {
  (void)in_sizes; (void)n_in; (void)out_size; (void)ws_size;
  const float* h     = (const float*)d_in[0];
  const float* adj   = (const float*)d_in[1];
  const float* edge  = (const float*)d_in[2];
  const float* srcm  = (const float*)d_in[3];
  const float* gcn_w = (const float*)d_in[4];
  const float* gcn_b = (const float*)d_in[5];
  const float* edge_w= (const float*)d_in[6];
  const float* edge_b= (const float*)d_in[7];
  const float* wq    = (const float*)d_in[8];
  const float* wk    = (const float*)d_in[9];
  const float* wv    = (const float*)d_in[10];
  const float* bq    = (const float*)d_in[11];
  const float* bk    = (const float*)d_in[12];
  const float* bv    = (const float*)d_in[13];
  const float* out_w = (const float*)d_in[14];
  const float* out_b = (const float*)d_in[15];
  const float* ln_g  = (const float*)d_in[16];
  const float* ln_b  = (const float*)d_in[17];

  float* ws  = (float*)d_ws;   // needs >= 4.59 MB
  float* out = (float*)d_out;

  prep_kernel<<<353, 256, 0, stream>>>(wq, wk, wv, out_w, gcn_w, edge_w, edge_b, bk, bv, ws);
  proj_kernel<<<1024, 256, 0, stream>>>(h, adj, bq, gcn_b, ws);
  attn_kernel<<<2048, 256, 0, stream>>>(edge, adj, srcm, h, out_b, ln_g, ln_b, ws, out);
}